// Round 7
// baseline (204.960 us; speedup 1.0000x reference)
//
#include <hip/hip_runtime.h>

// ============================ AUDIT ROUND ============================
// R3 kernel body executed 4x per launch (idempotent re-compute + re-store)
// purely to push our dispatch above the harness's ~48us fills into the
// rocprof top-5 and obtain VALUBusy / MfmaUtil / OccupancyPercent /
// SQ_LDS_BANK_CONFLICT / FETCH / WRITE for OUR kernel for the first time.
// Timing regression this round is intentional and will be reverted.
// =====================================================================

#define NG 100    // graph size
#define DD 128    // feature dim
#define NPAD 112  // 7 * 16
#define LSTRIDE 136  // LDS row stride in bf16 elems (bank-balanced b128 reads)
#define NPASS 4   // audit repeats

typedef __attribute__((ext_vector_type(8))) short bf16x8;
typedef __attribute__((ext_vector_type(4))) float floatx4;

__global__ __launch_bounds__(256, 4)
void dotdec_mfma_audit(const float* __restrict__ x, float* __restrict__ out) {
    __shared__ __align__(16) char smraw[NG * NG * 4];   // 40,000 B
    unsigned short* xs = (unsigned short*)smraw;         // [NPAD][LSTRIDE] bf16 staging
    float*          fo = (float*)smraw;                  // [NG][NG] fp32 output staging

    const int t    = threadIdx.x;
    const int lane = t & 63;
    const int wave = t >> 6;
    const int quad = lane >> 4;
    const int lr   = lane & 15;
    const size_t b = blockIdx.x;
    const float* xb = x   + b * (size_t)(NG * DD);
    float*       ob = out + b * (size_t)(NG * NG);

    for (int pass = 0; pass < NPASS; ++pass) {
        if (pass) __syncthreads();   // prior pass's fo reads done before xs overwrite

        // ---- zero pad rows 100..111 ----
        if (t < 192) {
            int r = 100 + (t >> 4), c = t & 15;
            *(uint4*)&xs[r * LSTRIDE + c * 8] = make_uint4(0u, 0u, 0u, 0u);
        }
        // ---- stage X fp32 -> bf16 (truncate), 32B/lane loads, b128 LDS writes ----
#pragma unroll
        for (int k = 0; k < 7; ++k) {
            int p = t + 256 * k;
            if (p < NG * 16) {
                int n = p >> 4, gp = p & 15;
                float4 v0 = ((const float4*)xb)[n * 32 + gp * 2];
                float4 v1 = ((const float4*)xb)[n * 32 + gp * 2 + 1];
                unsigned int u0 = (__float_as_uint(v0.x) >> 16) | (__float_as_uint(v0.y) & 0xffff0000u);
                unsigned int u1 = (__float_as_uint(v0.z) >> 16) | (__float_as_uint(v0.w) & 0xffff0000u);
                unsigned int u2 = (__float_as_uint(v1.x) >> 16) | (__float_as_uint(v1.y) & 0xffff0000u);
                unsigned int u3 = (__float_as_uint(v1.z) >> 16) | (__float_as_uint(v1.w) & 0xffff0000u);
                *(uint4*)&xs[n * LSTRIDE + gp * 8] = make_uint4(u0, u1, u2, u3);
            }
        }
        __syncthreads();

        // ---- MFMA GEMM: 7x7 tiles, wave owns tile-cols c0=wave, c1=wave+4 ----
        const int c0 = wave;
        const int c1 = (wave < 3) ? wave + 4 : wave;
        floatx4 acc0[7], acc1[7];
#pragma unroll
        for (int r = 0; r < 7; ++r) {
            acc0[r] = (floatx4){0.f, 0.f, 0.f, 0.f};
            acc1[r] = (floatx4){0.f, 0.f, 0.f, 0.f};
        }
#pragma unroll
        for (int k = 0; k < 4; ++k) {
            const int koff = k * 32 + quad * 8;
            bf16x8 b0 = *(const bf16x8*)&xs[(c0 * 16 + lr) * LSTRIDE + koff];
            bf16x8 b1 = *(const bf16x8*)&xs[(c1 * 16 + lr) * LSTRIDE + koff];
#pragma unroll
            for (int r = 0; r < 7; ++r) {
                bf16x8 a = *(const bf16x8*)&xs[(r * 16 + lr) * LSTRIDE + koff];
                acc0[r] = __builtin_amdgcn_mfma_f32_16x16x32_bf16(a, b0, acc0[r], 0, 0, 0);
                acc1[r] = __builtin_amdgcn_mfma_f32_16x16x32_bf16(a, b1, acc1[r], 0, 0, 0);
            }
        }

        // ---- column max (lane owns cols m0=c0*16+lr, m1=c1*16+lr) ----
        float mx0 = -3.402823466e38f, mx1 = -3.402823466e38f;
#pragma unroll
        for (int r = 0; r < 6; ++r)
#pragma unroll
            for (int i = 0; i < 4; ++i) {
                mx0 = fmaxf(mx0, acc0[r][i]);
                mx1 = fmaxf(mx1, acc1[r][i]);
            }
        if (quad == 0)
#pragma unroll
            for (int i = 0; i < 4; ++i) {
                mx0 = fmaxf(mx0, acc0[6][i]);
                mx1 = fmaxf(mx1, acc1[6][i]);
            }
        mx0 = fmaxf(mx0, __shfl_xor(mx0, 16, 64));
        mx0 = fmaxf(mx0, __shfl_xor(mx0, 32, 64));
        mx1 = fmaxf(mx1, __shfl_xor(mx1, 16, 64));
        mx1 = fmaxf(mx1, __shfl_xor(mx1, 32, 64));

        // ---- exp + column sum ----
        float s0 = 0.f, s1 = 0.f;
#pragma unroll
        for (int r = 0; r < 6; ++r)
#pragma unroll
            for (int i = 0; i < 4; ++i) {
                float e0 = __expf(acc0[r][i] - mx0); acc0[r][i] = e0; s0 += e0;
                float e1 = __expf(acc1[r][i] - mx1); acc1[r][i] = e1; s1 += e1;
            }
        if (quad == 0)
#pragma unroll
            for (int i = 0; i < 4; ++i) {
                float e0 = __expf(acc0[6][i] - mx0); acc0[6][i] = e0; s0 += e0;
                float e1 = __expf(acc1[6][i] - mx1); acc1[6][i] = e1; s1 += e1;
            }
        s0 += __shfl_xor(s0, 16, 64); s0 += __shfl_xor(s0, 32, 64);
        s1 += __shfl_xor(s1, 16, 64); s1 += __shfl_xor(s1, 32, 64);
        const float r0 = __builtin_amdgcn_rcpf(s0);
        const float r1 = __builtin_amdgcn_rcpf(s1);

        // ---- transpose through LDS, then coalesced copy-out ----
        __syncthreads();
        const int m0 = c0 * 16 + lr;
        const int m1 = c1 * 16 + lr;
        const bool dual = (c1 != c0) && (m1 < NG);
#pragma unroll
        for (int r = 0; r < 6; ++r)
#pragma unroll
            for (int i = 0; i < 4; ++i) {
                int n = r * 16 + quad * 4 + i;
                fo[n * NG + m0] = acc0[r][i] * r0;
                if (dual) fo[n * NG + m1] = acc1[r][i] * r1;
            }
        if (quad == 0)
#pragma unroll
            for (int i = 0; i < 4; ++i) {
                int n = 96 + i;
                fo[n * NG + m0] = acc0[6][i] * r0;
                if (dual) fo[n * NG + m1] = acc1[6][i] * r1;
            }
        __syncthreads();

#pragma unroll
        for (int k = 0; k < 10; ++k) {
            int f = t + 256 * k;
            if (f < (NG * NG) / 4)
                ((float4*)ob)[f] = *(const float4*)&fo[f * 4];
        }
    }
}

extern "C" void kernel_launch(void* const* d_in, const int* in_sizes, int n_in,
                              void* d_out, int out_size, void* d_ws, size_t ws_size,
                              hipStream_t stream) {
    const float* x = (const float*)d_in[0];
    // d_in[1] (edge_index) and d_in[2] (graph_size) are dead in the reference math.
    float* out = (float*)d_out;
    const int B = in_sizes[0] / (NG * DD);   // 1024
    hipLaunchKernelGGL(dotdec_mfma_audit, dim3(B), dim3(256), 0, stream, x, out);
}

// Round 8
// 156.466 us; speedup vs baseline: 1.3099x; 1.3099x over previous
//
#include <hip/hip_runtime.h>

#define NG 100    // graph size
#define DD 128    // feature dim
#define NPAD 112  // 7 * 16
#define LSTRIDE 136  // LDS row stride in bf16 elems (bank-balanced b128 reads)

typedef __attribute__((ext_vector_type(8))) short bf16x8;
typedef __attribute__((ext_vector_type(4))) float floatx4;

// pack truncated-bf16 of (lo,hi) into one uint via a single v_perm_b32
__device__ __forceinline__ unsigned pack2(float lo, float hi) {
    return __builtin_amdgcn_perm(__float_as_uint(hi), __float_as_uint(lo), 0x07060302u);
}

// R3 body with K-SPLIT PIPELINED STAGING (audit R7 showed: hot body ~17us at
// 80% TCC BW; single pass ~36us -> ~19us cold ramp where every block waits for
// its full 51KB X-slice before the first MFMA). K=128 = 4 quarters of 32 =
// exactly one MFMA k-step each; quarters hit DISJOINT LDS columns -> one
// barrier per quarter, no double buffer. Quarter q+1's global loads are issued
// before quarter q's GEMM; first MFMA now waits on 13MB aggregate, not 52MB.
__global__ __launch_bounds__(256, 4)
void dotdec_kpipe(const float* __restrict__ x, float* __restrict__ out) {
    __shared__ __align__(16) char smraw[NG * NG * 4];   // 40,000 B
    unsigned short* xs = (unsigned short*)smraw;         // [NPAD][LSTRIDE] bf16 staging
    float*          fo = (float*)smraw;                  // [NG][NG] fp32 out staging

    const int t    = threadIdx.x;
    const int lane = t & 63;
    const int wave = t >> 6;
    const int quad = lane >> 4;
    const int lr   = lane & 15;
    const size_t b = blockIdx.x;
    const float* xb = x   + b * (size_t)(NG * DD);
    float*       ob = out + b * (size_t)(NG * NG);
    const float4* xb4 = (const float4*)xb;

    // ---- zero pad rows 100..111 (all 128 cols; staging never rewrites them) ----
    if (t < 192) {
        int r = 100 + (t >> 4), c = t & 15;
        *(uint4*)&xs[r * LSTRIDE + c * 8] = make_uint4(0u, 0u, 0u, 0u);
    }

    // thread's staging slots (invariant across quarters): float4 f = t+256j -> row, chunk
    int  sn[4], sc[4];
    bool sv[4];
#pragma unroll
    for (int j = 0; j < 4; ++j) {
        int f = t + 256 * j;          // quarter = 100 rows x 8 float4 = 800 slots
        sv[j] = (f < 800);
        sn[j] = f >> 3;
        sc[j] = f & 7;
    }

    // ---- stage quarter 0 (k-cols 0..31) ----
#pragma unroll
    for (int j = 0; j < 4; ++j) {
        if (sv[j]) {
            float4 v = xb4[sn[j] * 32 + sc[j]];
            *(uint2*)&xs[sn[j] * LSTRIDE + sc[j] * 4] =
                make_uint2(pack2(v.x, v.y), pack2(v.z, v.w));
        }
    }
    __syncthreads();

    // ---- pipelined GEMM over quarters ----
    const int c0 = wave;
    const int c1 = (wave < 3) ? wave + 4 : wave;   // wave3 dup (stores skipped)
    floatx4 acc0[7], acc1[7];
#pragma unroll
    for (int r = 0; r < 7; ++r) {
        acc0[r] = (floatx4){0.f, 0.f, 0.f, 0.f};
        acc1[r] = (floatx4){0.f, 0.f, 0.f, 0.f};
    }

#pragma unroll
    for (int q = 0; q < 4; ++q) {
        // issue next quarter's global loads FIRST (fly under this quarter's GEMM)
        float4 pre[4];
        if (q < 3) {
#pragma unroll
            for (int j = 0; j < 4; ++j)
                if (sv[j]) pre[j] = xb4[sn[j] * 32 + (q + 1) * 8 + sc[j]];
        }

        const int koff = q * 32 + quad * 8;
        bf16x8 bb0 = *(const bf16x8*)&xs[(c0 * 16 + lr) * LSTRIDE + koff];
        bf16x8 bb1 = *(const bf16x8*)&xs[(c1 * 16 + lr) * LSTRIDE + koff];
#pragma unroll
        for (int r = 0; r < 7; ++r) {
            bf16x8 aa = *(const bf16x8*)&xs[(r * 16 + lr) * LSTRIDE + koff];
            acc0[r] = __builtin_amdgcn_mfma_f32_16x16x32_bf16(aa, bb0, acc0[r], 0, 0, 0);
            acc1[r] = __builtin_amdgcn_mfma_f32_16x16x32_bf16(aa, bb1, acc1[r], 0, 0, 0);
        }

        if (q < 3) {
            // land quarter q+1 (disjoint LDS columns -> no read/write hazard w/ q)
#pragma unroll
            for (int j = 0; j < 4; ++j)
                if (sv[j])
                    *(uint2*)&xs[sn[j] * LSTRIDE + ((q + 1) * 8 + sc[j]) * 4] =
                        make_uint2(pack2(pre[j].x, pre[j].y), pack2(pre[j].z, pre[j].w));
            __syncthreads();   // quarter q+1 visible to all waves
        }
    }

    // ---- column max (lane owns cols m0=c0*16+lr, m1=c1*16+lr) — R3 verbatim ----
    float mx0 = -3.402823466e38f, mx1 = -3.402823466e38f;
#pragma unroll
    for (int r = 0; r < 6; ++r)
#pragma unroll
        for (int i = 0; i < 4; ++i) {
            mx0 = fmaxf(mx0, acc0[r][i]);
            mx1 = fmaxf(mx1, acc1[r][i]);
        }
    if (quad == 0)
#pragma unroll
        for (int i = 0; i < 4; ++i) {
            mx0 = fmaxf(mx0, acc0[6][i]);
            mx1 = fmaxf(mx1, acc1[6][i]);
        }
    mx0 = fmaxf(mx0, __shfl_xor(mx0, 16, 64));
    mx0 = fmaxf(mx0, __shfl_xor(mx0, 32, 64));
    mx1 = fmaxf(mx1, __shfl_xor(mx1, 16, 64));
    mx1 = fmaxf(mx1, __shfl_xor(mx1, 32, 64));

    // ---- exp + column sum ----
    float s0 = 0.f, s1 = 0.f;
#pragma unroll
    for (int r = 0; r < 6; ++r)
#pragma unroll
        for (int i = 0; i < 4; ++i) {
            float e0 = __expf(acc0[r][i] - mx0); acc0[r][i] = e0; s0 += e0;
            float e1 = __expf(acc1[r][i] - mx1); acc1[r][i] = e1; s1 += e1;
        }
    if (quad == 0)
#pragma unroll
        for (int i = 0; i < 4; ++i) {
            float e0 = __expf(acc0[6][i] - mx0); acc0[6][i] = e0; s0 += e0;
            float e1 = __expf(acc1[6][i] - mx1); acc1[6][i] = e1; s1 += e1;
        }
    s0 += __shfl_xor(s0, 16, 64); s0 += __shfl_xor(s0, 32, 64);
    s1 += __shfl_xor(s1, 16, 64); s1 += __shfl_xor(s1, 32, 64);
    const float r0 = __builtin_amdgcn_rcpf(s0);   // outputs in [0,1]
    const float r1 = __builtin_amdgcn_rcpf(s1);

    // ---- transpose through LDS, then coalesced copy-out — R3 verbatim ----
    __syncthreads();   // all GEMM ds_reads done before fo overwrites xs
    const int m0 = c0 * 16 + lr;
    const int m1 = c1 * 16 + lr;
    const bool dual = (c1 != c0) && (m1 < NG);
#pragma unroll
    for (int r = 0; r < 6; ++r)
#pragma unroll
        for (int i = 0; i < 4; ++i) {
            int n = r * 16 + quad * 4 + i;
            fo[n * NG + m0] = acc0[r][i] * r0;    // 2-way bank alias: free (audit: ~1%)
            if (dual) fo[n * NG + m1] = acc1[r][i] * r1;
        }
    if (quad == 0)
#pragma unroll
        for (int i = 0; i < 4; ++i) {
            int n = 96 + i;
            fo[n * NG + m0] = acc0[6][i] * r0;
            if (dual) fo[n * NG + m1] = acc1[6][i] * r1;
        }
    __syncthreads();

#pragma unroll
    for (int k = 0; k < 10; ++k) {
        int f = t + 256 * k;
        if (f < (NG * NG) / 4)
            ((float4*)ob)[f] = *(const float4*)&fo[f * 4];   // fully coalesced
    }
}

extern "C" void kernel_launch(void* const* d_in, const int* in_sizes, int n_in,
                              void* d_out, int out_size, void* d_ws, size_t ws_size,
                              hipStream_t stream) {
    const float* x = (const float*)d_in[0];
    // d_in[1] (edge_index) and d_in[2] (graph_size) are dead in the reference math.
    float* out = (float*)d_out;
    const int B = in_sizes[0] / (NG * DD);   // 1024
    hipLaunchKernelGGL(dotdec_kpipe, dim3(B), dim3(256), 0, stream, x, out);
}